// Round 17
// baseline (144.945 us; speedup 1.0000x reference)
//
#include <hip/hip_runtime.h>
#include <hip/hip_bf16.h>

typedef unsigned short u16;
typedef __attribute__((ext_vector_type(4))) float f32x4;
typedef __attribute__((ext_vector_type(8))) __bf16 bf16x8;

#define NH 16
#define HD 64
#define HID 1024
#define SS 2048
#define MM 4096

__device__ __forceinline__ u16 f2b(float f) {
  unsigned u = __builtin_bit_cast(unsigned, f);
  u += 0x7fff + ((u >> 16) & 1);   // RNE
  return (u16)(u >> 16);
}

__device__ __forceinline__ float fexp2(float x) {
#if __has_builtin(__builtin_amdgcn_exp2f)
  return __builtin_amdgcn_exp2f(x);
#else
  return exp2f(x);
#endif
}

// DPP lane-permute within a 16-lane row (VALU pipe — zero DS traffic)
template <int CTRL>
__device__ __forceinline__ float dpp_mv(float x) {
  int xi = __builtin_bit_cast(int, x);
  int yi = __builtin_amdgcn_update_dpp(xi, xi, CTRL, 0xF, 0xF, true);
  return __builtin_bit_cast(float, yi);
}
__device__ __forceinline__ float dppmax16(float v) {
  v = fmaxf(v, dpp_mv<0xB1>(v));
  v = fmaxf(v, dpp_mv<0x4E>(v));
  v = fmaxf(v, dpp_mv<0x141>(v));
  v = fmaxf(v, dpp_mv<0x140>(v));
  return v;
}
__device__ __forceinline__ float dppsum16(float v) {
  v += dpp_mv<0xB1>(v);
  v += dpp_mv<0x4E>(v);
  v += dpp_mv<0x141>(v);
  v += dpp_mv<0x140>(v);
  return v;
}

// async global -> LDS, 16B per lane (wave-uniform LDS base + lane*16)
__device__ __forceinline__ void gl_lds16(const u16* g, u16* l) {
  __builtin_amdgcn_global_load_lds(
      (const __attribute__((address_space(1))) void*)g,
      (__attribute__((address_space(3))) void*)l, 16, 0, 0);
}

// ---------------- fused fp32 -> bf16 conversion (x + 4 weights, 1 launch) ---
__global__ void cvt_all(const float* __restrict__ hs,
                        const float* __restrict__ wq, const float* __restrict__ wk,
                        const float* __restrict__ wv, const float* __restrict__ wo,
                        u16* __restrict__ xb, u16* __restrict__ wqb,
                        u16* __restrict__ wkb, u16* __restrict__ wvb,
                        u16* __restrict__ wob) {
  const int i = blockIdx.x * 256 + threadIdx.x;   // float4 index, 2M total
  const float* src; u16* dst; int off;
  if (i < 1048576) { src = hs; dst = xb; off = i; }
  else {
    const int j = i - 1048576;
    const int w = j >> 18;          // 262144 float4s per weight
    off = j & 262143;
    src = (w == 0) ? wq : (w == 1) ? wk : (w == 2) ? wv : wo;
    dst = (w == 0) ? wqb : (w == 1) ? wkb : (w == 2) ? wvb : wob;
  }
  float4 v = reinterpret_cast<const float4*>(src)[off];
  ushort4 o;
  o.x = f2b(v.x); o.y = f2b(v.y); o.z = f2b(v.z); o.w = f2b(v.w);
  reinterpret_cast<ushort4*>(dst)[off] = o;
}

// ---------------- fused QKV projection (BK=64, swizzled gl_lds staging) -----
// V blocks (wi==2) use SWAPPED mfma operands (verified v14 rule: 1st operand
// -> row/reg, 2nd -> col/lane) so the transposed vt store has lane index on
// the s dimension: 32B-contiguous segments instead of 16-line 2B scatter.
__global__ __launch_bounds__(256)
void gemm_qkv(const u16* __restrict__ xb,
              const u16* __restrict__ wqb, const u16* __restrict__ wkb, const u16* __restrict__ wvb,
              const float* __restrict__ bq, const float* __restrict__ bk, const float* __restrict__ bv,
              u16* __restrict__ qh, u16* __restrict__ kh, u16* __restrict__ vt) {
  const int mt = blockIdx.x;             // 0..31
  const int nt = blockIdx.y;             // 0..23
  const int wi = nt >> 3;                // 0=q 1=k 2=v
  const int n0 = (nt & 7) << 7;
  const int m0 = mt << 7;
  const u16* wb = (wi == 0) ? wqb : (wi == 1) ? wkb : wvb;
  const float* bias = (wi == 0) ? bq : (wi == 1) ? bk : bv;

  __shared__ u16 at[128 * 64];   // 16KB, slot-swizzled
  __shared__ u16 bt[128 * 64];

  const int tid = threadIdx.x;
  const int wave = tid >> 6;
  const int lane = tid & 63;
  const int g = lane >> 4;
  const int wm = (wave >> 1) << 6;
  const int wn = (wave & 1) << 6;
  const int lr = lane & 15;
  const int rb = g << 2;
  const int lrow = lane >> 3;
  const int dslot = lane & 7;

  f32x4 acc[4][4] = {};

  for (int k0 = 0; k0 < HID; k0 += 64) {
    __syncthreads();
    #pragma unroll
    for (int i = 0; i < 4; i++) {
      const int row = wave * 32 + i * 8 + lrow;
      const int scol = (dslot ^ (row & 7)) << 3;
      gl_lds16(&xb[(size_t)(m0 + row) * HID + k0 + scol], at + wave * 2048 + i * 512);
      gl_lds16(&wb[(size_t)(n0 + row) * HID + k0 + scol], bt + wave * 2048 + i * 512);
    }
    __syncthreads();
    #pragma unroll
    for (int kk = 0; kk < 2; kk++) {
      bf16x8 af[4], bfr[4];
      #pragma unroll
      for (int i = 0; i < 4; i++) {
        const int ra = wm + i * 16 + lr;
        const int rbw = wn + i * 16 + lr;
        const int sa_ = ((kk << 2) + g) ^ (ra & 7);
        const int sb_ = ((kk << 2) + g) ^ (rbw & 7);
        af[i]  = *reinterpret_cast<const bf16x8*>(&at[ra * 64 + (sa_ << 3)]);
        bfr[i] = *reinterpret_cast<const bf16x8*>(&bt[rbw * 64 + (sb_ << 3)]);
      }
      if (wi != 2) {
        #pragma unroll
        for (int i = 0; i < 4; i++)
          #pragma unroll
          for (int j = 0; j < 4; j++)
            acc[i][j] = __builtin_amdgcn_mfma_f32_16x16x32_bf16(af[i], bfr[j], acc[i][j], 0, 0, 0);
      } else {
        // swapped: acc[i][j] holds D[n-sub j: row=rb+r][m-sub i: col=lr]
        #pragma unroll
        for (int i = 0; i < 4; i++)
          #pragma unroll
          for (int j = 0; j < 4; j++)
            acc[i][j] = __builtin_amdgcn_mfma_f32_16x16x32_bf16(bfr[j], af[i], acc[i][j], 0, 0, 0);
      }
    }
  }

  if (wi != 2) {
    #pragma unroll
    for (int i = 0; i < 4; i++) {
      #pragma unroll
      for (int j = 0; j < 4; j++) {
        #pragma unroll
        for (int r = 0; r < 4; r++) {
          const int m = m0 + wm + i * 16 + rb + r;
          const int n = n0 + wn + j * 16 + lr;
          const float val = acc[i][j][r] + bias[n];
          const u16 bv16 = f2b(val);
          const int b = m >> 11, s = m & 2047;
          const int h = n >> 6, d = n & 63;
          if (wi == 0) qh[((size_t)(b * NH + h) * SS + s) * HD + d] = bv16;
          else         kh[((size_t)(b * NH + h) * SS + s) * HD + d] = bv16;
        }
      }
    }
  } else {
    #pragma unroll
    for (int i = 0; i < 4; i++) {
      #pragma unroll
      for (int j = 0; j < 4; j++) {
        #pragma unroll
        for (int r = 0; r < 4; r++) {
          const int n = n0 + wn + j * 16 + rb + r;   // row side (1st operand)
          const int m = m0 + wm + i * 16 + lr;       // col side (2nd operand)
          const float val = acc[i][j][r] + bias[n];
          const u16 bv16 = f2b(val);
          const int b = m >> 11, s = m & 2047;
          const int h = n >> 6, d = n & 63;
          vt[((size_t)(b * NH + h) * HD + d) * SS + s] = bv16;
        }
      }
    }
  }
}

// ---------------- flash attention v16: v12 math + 3-deep counted-vmcnt ------
__global__ __launch_bounds__(256, 2)
void attn(const u16* __restrict__ qh, const u16* __restrict__ kh, const u16* __restrict__ vt,
          const float* __restrict__ mask, u16* __restrict__ ctxb) {
  const int id = blockIdx.x;
  const int bh = (id & 7) + 8 * ((id >> 3) & 3);
  const int qt = id >> 5;                         // 0..15
  const int b = bh >> 4;
  const int h = bh & 15;
  const int q0 = qt << 7;                         // 128 q-rows per block

  const int tid = threadIdx.x;
  const int wave = tid >> 6;
  const int lane = tid & 63;
  const int g = lane >> 4;
  const int lr = lane & 15;
  const int lk = g << 3;
  const int rb = g << 2;
  const int lrow = lane >> 3;
  const int dslot = lane & 7;

  const u16* qb = qh + (size_t)bh * SS * HD;
  const u16* kb = kh + (size_t)bh * SS * HD;
  const u16* vb = vt + (size_t)bh * HD * SS;
  const float* mrow = mask + (size_t)b * SS;

  __shared__ u16 kt[3][64 * 64];     // K tile [kv][64d], swizzled, 8KB x3
  __shared__ u16 vtile[3][64 * 64];  // V^T tile [d][64kv], swizzled, 8KB x3
  __shared__ u16 pt[4][32][72];      // per-wave P buffer, 2 chains x 16 rows

  const int qrow0 = q0 + wave * 32;

  bf16x8 qf[2][2];
  #pragma unroll
  for (int c = 0; c < 2; c++)
    #pragma unroll
    for (int dk = 0; dk < 2; dk++)
      qf[c][dk] = *reinterpret_cast<const bf16x8*>(
          &qb[(size_t)(qrow0 + c * 16 + lr) * HD + dk * 32 + lk]);

  f32x4 o[2][4] = {};
  float mrun[2][4], lrun[2][4];   // lrun = per-LANE partial sums
  #pragma unroll
  for (int c = 0; c < 2; c++)
    #pragma unroll
    for (int r = 0; r < 4; r++) { mrun[c][r] = -1e30f; lrun[c][r] = 0.f; }

  const float LOG2E = 1.4426950408889634f;
  const float SCL = 0.125f * LOG2E;

  auto stage = [&](u16* kdst, u16* vdst, int kv0) {
    #pragma unroll
    for (int i = 0; i < 2; i++) {
      const int row = wave * 16 + i * 8 + lrow;
      const int scol = (dslot ^ (row & 7)) << 3;
      gl_lds16(&kb[(size_t)(kv0 + row) * HD + scol], kdst + wave * 1024 + i * 512);
      gl_lds16(&vb[(size_t)row * SS + kv0 + scol], vdst + wave * 1024 + i * 512);
    }
  };

  // prologue: 2 tiles in flight (8 gl_lds outstanding per wave)
  stage(kt[0], vtile[0], 0);
  stage(kt[1], vtile[1], 64);

  for (int it = 0; it < SS / 64; ++it) {
    if (it < SS / 64 - 1) asm volatile("s_waitcnt vmcnt(4)" ::: "memory");
    else                  asm volatile("s_waitcnt vmcnt(0)" ::: "memory");
    __builtin_amdgcn_s_barrier();

    const int cur = it % 3;
    if (it + 2 < SS / 64) {
      const int nxt = (it + 2) % 3;
      stage(kt[nxt], vtile[nxt], (it + 2) * 64);
    }

    const int kv0 = it * 64;
    const u16* kc = kt[cur];
    const u16* vc = vtile[cur];

    // S = Q K^T — K fragments read ONCE, used by both chains
    f32x4 sa[2][4] = {};
    #pragma unroll
    for (int ks = 0; ks < 4; ks++) {
      const int row = ks * 16 + lr;
      const int s0 = g ^ (row & 7);
      const int s1 = (g + 4) ^ (row & 7);
      const bf16x8 kf0 = *reinterpret_cast<const bf16x8*>(&kc[row * 64 + (s0 << 3)]);
      const bf16x8 kf1 = *reinterpret_cast<const bf16x8*>(&kc[row * 64 + (s1 << 3)]);
      #pragma unroll
      for (int c = 0; c < 2; c++) {
        sa[c][ks] = __builtin_amdgcn_mfma_f32_16x16x32_bf16(qf[c][0], kf0, sa[c][ks], 0, 0, 0);
        sa[c][ks] = __builtin_amdgcn_mfma_f32_16x16x32_bf16(qf[c][1], kf1, sa[c][ks], 0, 0, 0);
      }
    }

    float mk2[4];
    #pragma unroll
    for (int ks = 0; ks < 4; ks++) mk2[ks] = mrow[kv0 + ks * 16 + lr] * LOG2E;

    // scale + mask + per-LANE local max (no tree on the common path)
    float tmax[2][4];
    #pragma unroll
    for (int c = 0; c < 2; c++) {
      #pragma unroll
      for (int r = 0; r < 4; r++) tmax[c][r] = -1e30f;
      #pragma unroll
      for (int ks = 0; ks < 4; ks++)
        #pragma unroll
        for (int r = 0; r < 4; r++) {
          const float v = fmaf(sa[c][ks][r], SCL, mk2[ks]);
          sa[c][ks][r] = v;
          tmax[c][r] = fmaxf(tmax[c][r], v);
        }
    }

    // T13 defer: __all over per-lane local maxima; tree only on rescale path
    float need = -1e30f;
    #pragma unroll
    for (int c = 0; c < 2; c++)
      #pragma unroll
      for (int r = 0; r < 4; r++) need = fmaxf(need, tmax[c][r] - mrun[c][r]);
    if (!__all(need <= 4.0f)) {
      #pragma unroll
      for (int c = 0; c < 2; c++)
        #pragma unroll
        for (int r = 0; r < 4; r++) {
          const float rowmax = dppmax16(tmax[c][r]);
          const float mnew = fmaxf(mrun[c][r], rowmax);
          const float alpha = fexp2(mrun[c][r] - mnew);
          mrun[c][r] = mnew;
          lrun[c][r] *= alpha;
          #pragma unroll
          for (int ds = 0; ds < 4; ds++) o[c][ds][r] *= alpha;
        }
    }

    // exp + per-lane sum accumulate; P -> LDS via f2b (verified path)
    #pragma unroll
    for (int c = 0; c < 2; c++)
      #pragma unroll
      for (int ks = 0; ks < 4; ks++)
        #pragma unroll
        for (int r = 0; r < 4; r++) {
          const float p = fexp2(sa[c][ks][r] - mrun[c][r]);
          lrun[c][r] += p;
          pt[wave][c * 16 + rb + r][ks * 16 + lr] = f2b(p);
        }

    bf16x8 pa[2][2];
    #pragma unroll
    for (int c = 0; c < 2; c++)
      #pragma unroll
      for (int ko = 0; ko < 2; ko++)
        pa[c][ko] = *reinterpret_cast<const bf16x8*>(&pt[wave][c * 16 + lr][ko * 32 + lk]);

    // O += P V — V fragments read ONCE, used by both chains
    #pragma unroll
    for (int ds = 0; ds < 4; ds++) {
      #pragma unroll
      for (int ko = 0; ko < 2; ko++) {
        const int vrow = ds * 16 + lr;
        const int vs = ((ko << 2) + g) ^ (vrow & 7);
        const bf16x8 vf = *reinterpret_cast<const bf16x8*>(&vc[vrow * 64 + (vs << 3)]);
        #pragma unroll
        for (int c = 0; c < 2; c++)
          o[c][ds] = __builtin_amdgcn_mfma_f32_16x16x32_bf16(pa[c][ko], vf, o[c][ds], 0, 0, 0);
      }
    }
  }

  // epilogue: ONE sum tree per (chain,row), then scale + store
  #pragma unroll
  for (int c = 0; c < 2; c++) {
    float inv[4];
    #pragma unroll
    for (int r = 0; r < 4; r++) inv[r] = 1.0f / dppsum16(lrun[c][r]);
    #pragma unroll
    for (int ds = 0; ds < 4; ds++)
      #pragma unroll
      for (int r = 0; r < 4; r++) {
        const int srow = qrow0 + c * 16 + rb + r;
        ctxb[(size_t)(b * SS + srow) * HID + h * HD + ds * 16 + lr] = f2b(o[c][ds][r] * inv[r]);
      }
  }
}

// ---------------- output projection (BK=64 swizzled staging, fp32 out) -----
__global__ __launch_bounds__(256)
void gemm_out(const u16* __restrict__ ab, const u16* __restrict__ wb,
              const float* __restrict__ bias, float* __restrict__ out) {
  const int m0 = blockIdx.x << 7;
  const int n0 = blockIdx.y << 6;

  __shared__ u16 at[128 * 64];   // 16KB, slot-swizzled
  __shared__ u16 bt[64 * 64];    // 8KB

  const int tid = threadIdx.x;
  const int wave = tid >> 6;
  const int lane = tid & 63;
  const int g = lane >> 4;
  const int wm = wave << 5;
  const int lr = lane & 15;
  const int rb = g << 2;
  const int lrow = lane >> 3;
  const int dslot = lane & 7;

  f32x4 acc[2][4] = {};

  for (int k0 = 0; k0 < HID; k0 += 64) {
    __syncthreads();
    #pragma unroll
    for (int i = 0; i < 4; i++) {
      const int row = wave * 32 + i * 8 + lrow;
      const int scol = (dslot ^ (row & 7)) << 3;
      gl_lds16(&ab[(size_t)(m0 + row) * HID + k0 + scol], at + wave * 2048 + i * 512);
    }
    #pragma unroll
    for (int i = 0; i < 2; i++) {
      const int row = wave * 16 + i * 8 + lrow;
      const int scol = (dslot ^ (row & 7)) << 3;
      gl_lds16(&wb[(size_t)(n0 + row) * HID + k0 + scol], bt + wave * 1024 + i * 512);
    }
    __syncthreads();
    #pragma unroll
    for (int kk = 0; kk < 2; kk++) {
      bf16x8 af[2], bfr[4];
      #pragma unroll
      for (int i = 0; i < 2; i++) {
        const int ra = wm + i * 16 + lr;
        const int sa_ = ((kk << 2) + g) ^ (ra & 7);
        af[i] = *reinterpret_cast<const bf16x8*>(&at[ra * 64 + (sa_ << 3)]);
      }
      #pragma unroll
      for (int j = 0; j < 4; j++) {
        const int rbw = j * 16 + lr;
        const int sb_ = ((kk << 2) + g) ^ (rbw & 7);
        bfr[j] = *reinterpret_cast<const bf16x8*>(&bt[rbw * 64 + (sb_ << 3)]);
      }
      #pragma unroll
      for (int i = 0; i < 2; i++)
        #pragma unroll
        for (int j = 0; j < 4; j++)
          acc[i][j] = __builtin_amdgcn_mfma_f32_16x16x32_bf16(af[i], bfr[j], acc[i][j], 0, 0, 0);
    }
  }

  #pragma unroll
  for (int i = 0; i < 2; i++)
    #pragma unroll
    for (int j = 0; j < 4; j++)
      #pragma unroll
      for (int r = 0; r < 4; r++) {
        const int m = m0 + wm + i * 16 + rb + r;
        const int n = n0 + j * 16 + lr;
        out[(size_t)m * HID + n] = acc[i][j][r] + bias[n];
      }
}

extern "C" void kernel_launch(void* const* d_in, const int* in_sizes, int n_in,
                              void* d_out, int out_size, void* d_ws, size_t ws_size,
                              hipStream_t stream) {
  const float* hs   = (const float*)d_in[0];
  const float* mask = (const float*)d_in[1];
  const float* wq   = (const float*)d_in[2];
  const float* bq   = (const float*)d_in[3];
  const float* wk   = (const float*)d_in[4];
  const float* bk   = (const float*)d_in[5];
  const float* wv   = (const float*)d_in[6];
  const float* bv   = (const float*)d_in[7];
  const float* wo   = (const float*)d_in[8];
  const float* bo   = (const float*)d_in[9];
  float* out = (float*)d_out;

  char* ws = (char*)d_ws;
  u16* xb   = (u16*)(ws);                         // 8 MB  [4096][1024]
  u16* ctxb = (u16*)(ws + ((size_t)8  << 20));    // 8 MB  [4096][1024]
  u16* qhb  = (u16*)(ws + ((size_t)16 << 20));    // 8 MB  [32][2048][64]
  u16* khb  = (u16*)(ws + ((size_t)24 << 20));    // 8 MB
  u16* vtb  = (u16*)(ws + ((size_t)32 << 20));    // 8 MB  [32][64][2048]
  u16* wqb  = (u16*)(ws + ((size_t)40 << 20));    // 2 MB each
  u16* wkb  = (u16*)(ws + ((size_t)42 << 20));
  u16* wvb  = (u16*)(ws + ((size_t)44 << 20));
  u16* wob  = (u16*)(ws + ((size_t)46 << 20));

  cvt_all<<<8192, 256, 0, stream>>>(hs, wq, wk, wv, wo, xb, wqb, wkb, wvb, wob);

  gemm_qkv<<<dim3(32, 24), 256, 0, stream>>>(xb, wqb, wkb, wvb, bq, bk, bv, qhb, khb, vtb);
  attn<<<512, 256, 0, stream>>>(qhb, khb, vtb, mask, ctxb);
  gemm_out<<<dim3(32, 16), 256, 0, stream>>>(ctxb, wob, bo, out);
}

// Round 18
// 140.896 us; speedup vs baseline: 1.0287x; 1.0287x over previous
//
#include <hip/hip_runtime.h>
#include <hip/hip_bf16.h>

typedef unsigned short u16;
typedef __attribute__((ext_vector_type(4))) float f32x4;
typedef __attribute__((ext_vector_type(8))) __bf16 bf16x8;

#define NH 16
#define HD 64
#define HID 1024
#define SS 2048
#define MM 4096

__device__ __forceinline__ u16 f2b(float f) {
  unsigned u = __builtin_bit_cast(unsigned, f);
  u += 0x7fff + ((u >> 16) & 1);   // RNE
  return (u16)(u >> 16);
}

__device__ __forceinline__ float fexp2(float x) {
#if __has_builtin(__builtin_amdgcn_exp2f)
  return __builtin_amdgcn_exp2f(x);
#else
  return exp2f(x);
#endif
}

// DPP lane-permute within a 16-lane row (VALU pipe — zero DS traffic)
template <int CTRL>
__device__ __forceinline__ float dpp_mv(float x) {
  int xi = __builtin_bit_cast(int, x);
  int yi = __builtin_amdgcn_update_dpp(xi, xi, CTRL, 0xF, 0xF, true);
  return __builtin_bit_cast(float, yi);
}
__device__ __forceinline__ float dppmax16(float v) {
  v = fmaxf(v, dpp_mv<0xB1>(v));
  v = fmaxf(v, dpp_mv<0x4E>(v));
  v = fmaxf(v, dpp_mv<0x141>(v));
  v = fmaxf(v, dpp_mv<0x140>(v));
  return v;
}
__device__ __forceinline__ float dppsum16(float v) {
  v += dpp_mv<0xB1>(v);
  v += dpp_mv<0x4E>(v);
  v += dpp_mv<0x141>(v);
  v += dpp_mv<0x140>(v);
  return v;
}

// async global -> LDS, 16B per lane (wave-uniform LDS base + lane*16)
__device__ __forceinline__ void gl_lds16(const u16* g, u16* l) {
  __builtin_amdgcn_global_load_lds(
      (const __attribute__((address_space(1))) void*)g,
      (__attribute__((address_space(3))) void*)l, 16, 0, 0);
}

// ---------------- fused fp32 -> bf16 conversion (x + 4 weights, 1 launch) ---
__global__ void cvt_all(const float* __restrict__ hs,
                        const float* __restrict__ wq, const float* __restrict__ wk,
                        const float* __restrict__ wv, const float* __restrict__ wo,
                        u16* __restrict__ xb, u16* __restrict__ wqb,
                        u16* __restrict__ wkb, u16* __restrict__ wvb,
                        u16* __restrict__ wob) {
  const int i = blockIdx.x * 256 + threadIdx.x;   // float4 index, 2M total
  const float* src; u16* dst; int off;
  if (i < 1048576) { src = hs; dst = xb; off = i; }
  else {
    const int j = i - 1048576;
    const int w = j >> 18;          // 262144 float4s per weight
    off = j & 262143;
    src = (w == 0) ? wq : (w == 1) ? wk : (w == 2) ? wv : wo;
    dst = (w == 0) ? wqb : (w == 1) ? wkb : (w == 2) ? wvb : wob;
  }
  float4 v = reinterpret_cast<const float4*>(src)[off];
  ushort4 o;
  o.x = f2b(v.x); o.y = f2b(v.y); o.z = f2b(v.z); o.w = f2b(v.w);
  reinterpret_cast<ushort4*>(dst)[off] = o;
}

// ---------------- fused QKV projection (BK=64, swizzled gl_lds staging) -----
__global__ __launch_bounds__(256)
void gemm_qkv(const u16* __restrict__ xb,
              const u16* __restrict__ wqb, const u16* __restrict__ wkb, const u16* __restrict__ wvb,
              const float* __restrict__ bq, const float* __restrict__ bk, const float* __restrict__ bv,
              u16* __restrict__ qh, u16* __restrict__ kh, u16* __restrict__ vt) {
  const int mt = blockIdx.x;             // 0..31
  const int nt = blockIdx.y;             // 0..23
  const int wi = nt >> 3;                // 0=q 1=k 2=v
  const int n0 = (nt & 7) << 7;
  const int m0 = mt << 7;
  const u16* wb = (wi == 0) ? wqb : (wi == 1) ? wkb : wvb;
  const float* bias = (wi == 0) ? bq : (wi == 1) ? bk : bv;

  __shared__ u16 at[128 * 64];   // 16KB, slot-swizzled
  __shared__ u16 bt[128 * 64];

  const int tid = threadIdx.x;
  const int wave = tid >> 6;
  const int lane = tid & 63;
  const int g = lane >> 4;
  const int wm = (wave >> 1) << 6;
  const int wn = (wave & 1) << 6;
  const int lr = lane & 15;
  const int rb = g << 2;
  const int lrow = lane >> 3;
  const int dslot = lane & 7;

  f32x4 acc[4][4] = {};

  for (int k0 = 0; k0 < HID; k0 += 64) {
    __syncthreads();
    #pragma unroll
    for (int i = 0; i < 4; i++) {
      const int row = wave * 32 + i * 8 + lrow;
      const int scol = (dslot ^ (row & 7)) << 3;
      gl_lds16(&xb[(size_t)(m0 + row) * HID + k0 + scol], at + wave * 2048 + i * 512);
      gl_lds16(&wb[(size_t)(n0 + row) * HID + k0 + scol], bt + wave * 2048 + i * 512);
    }
    __syncthreads();
    #pragma unroll
    for (int kk = 0; kk < 2; kk++) {
      bf16x8 af[4], bfr[4];
      #pragma unroll
      for (int i = 0; i < 4; i++) {
        const int ra = wm + i * 16 + lr;
        const int rbw = wn + i * 16 + lr;
        const int sa_ = ((kk << 2) + g) ^ (ra & 7);
        const int sb_ = ((kk << 2) + g) ^ (rbw & 7);
        af[i]  = *reinterpret_cast<const bf16x8*>(&at[ra * 64 + (sa_ << 3)]);
        bfr[i] = *reinterpret_cast<const bf16x8*>(&bt[rbw * 64 + (sb_ << 3)]);
      }
      #pragma unroll
      for (int i = 0; i < 4; i++)
        #pragma unroll
        for (int j = 0; j < 4; j++)
          acc[i][j] = __builtin_amdgcn_mfma_f32_16x16x32_bf16(af[i], bfr[j], acc[i][j], 0, 0, 0);
    }
  }

  #pragma unroll
  for (int i = 0; i < 4; i++) {
    #pragma unroll
    for (int j = 0; j < 4; j++) {
      #pragma unroll
      for (int r = 0; r < 4; r++) {
        const int m = m0 + wm + i * 16 + rb + r;
        const int n = n0 + wn + j * 16 + lr;
        const float val = acc[i][j][r] + bias[n];
        const u16 bv16 = f2b(val);
        const int b = m >> 11, s = m & 2047;
        const int h = n >> 6, d = n & 63;
        if (wi == 0)      qh[((size_t)(b * NH + h) * SS + s) * HD + d] = bv16;
        else if (wi == 1) kh[((size_t)(b * NH + h) * SS + s) * HD + d] = bv16;
        else              vt[((size_t)(b * NH + h) * HD + d) * SS + s] = bv16;
      }
    }
  }
}

// ---------------- flash attention v16: v12 math + 3-deep counted-vmcnt ------
__global__ __launch_bounds__(256, 2)
void attn(const u16* __restrict__ qh, const u16* __restrict__ kh, const u16* __restrict__ vt,
          const float* __restrict__ mask, u16* __restrict__ ctxb) {
  const int id = blockIdx.x;
  const int bh = (id & 7) + 8 * ((id >> 3) & 3);
  const int qt = id >> 5;                         // 0..15
  const int b = bh >> 4;
  const int h = bh & 15;
  const int q0 = qt << 7;                         // 128 q-rows per block

  const int tid = threadIdx.x;
  const int wave = tid >> 6;
  const int lane = tid & 63;
  const int g = lane >> 4;
  const int lr = lane & 15;
  const int lk = g << 3;
  const int rb = g << 2;
  const int lrow = lane >> 3;
  const int dslot = lane & 7;

  const u16* qb = qh + (size_t)bh * SS * HD;
  const u16* kb = kh + (size_t)bh * SS * HD;
  const u16* vb = vt + (size_t)bh * HD * SS;
  const float* mrow = mask + (size_t)b * SS;

  __shared__ u16 kt[3][64 * 64];     // K tile [kv][64d], swizzled, 8KB x3
  __shared__ u16 vtile[3][64 * 64];  // V^T tile [d][64kv], swizzled, 8KB x3
  __shared__ u16 pt[4][32][72];      // per-wave P buffer, 2 chains x 16 rows

  const int qrow0 = q0 + wave * 32;

  bf16x8 qf[2][2];
  #pragma unroll
  for (int c = 0; c < 2; c++)
    #pragma unroll
    for (int dk = 0; dk < 2; dk++)
      qf[c][dk] = *reinterpret_cast<const bf16x8*>(
          &qb[(size_t)(qrow0 + c * 16 + lr) * HD + dk * 32 + lk]);

  f32x4 o[2][4] = {};
  float mrun[2][4], lrun[2][4];   // lrun = per-LANE partial sums
  #pragma unroll
  for (int c = 0; c < 2; c++)
    #pragma unroll
    for (int r = 0; r < 4; r++) { mrun[c][r] = -1e30f; lrun[c][r] = 0.f; }

  const float LOG2E = 1.4426950408889634f;
  const float SCL = 0.125f * LOG2E;

  auto stage = [&](u16* kdst, u16* vdst, int kv0) {
    #pragma unroll
    for (int i = 0; i < 2; i++) {
      const int row = wave * 16 + i * 8 + lrow;
      const int scol = (dslot ^ (row & 7)) << 3;
      gl_lds16(&kb[(size_t)(kv0 + row) * HD + scol], kdst + wave * 1024 + i * 512);
      gl_lds16(&vb[(size_t)row * SS + kv0 + scol], vdst + wave * 1024 + i * 512);
    }
  };

  // prologue: 2 tiles in flight (8 gl_lds outstanding per wave)
  stage(kt[0], vtile[0], 0);
  stage(kt[1], vtile[1], 64);

  for (int it = 0; it < SS / 64; ++it) {
    if (it < SS / 64 - 1) asm volatile("s_waitcnt vmcnt(4)" ::: "memory");
    else                  asm volatile("s_waitcnt vmcnt(0)" ::: "memory");
    __builtin_amdgcn_s_barrier();

    const int cur = it % 3;
    if (it + 2 < SS / 64) {
      const int nxt = (it + 2) % 3;
      stage(kt[nxt], vtile[nxt], (it + 2) * 64);
    }

    const int kv0 = it * 64;
    const u16* kc = kt[cur];
    const u16* vc = vtile[cur];

    // S = Q K^T — K fragments read ONCE, used by both chains
    f32x4 sa[2][4] = {};
    #pragma unroll
    for (int ks = 0; ks < 4; ks++) {
      const int row = ks * 16 + lr;
      const int s0 = g ^ (row & 7);
      const int s1 = (g + 4) ^ (row & 7);
      const bf16x8 kf0 = *reinterpret_cast<const bf16x8*>(&kc[row * 64 + (s0 << 3)]);
      const bf16x8 kf1 = *reinterpret_cast<const bf16x8*>(&kc[row * 64 + (s1 << 3)]);
      #pragma unroll
      for (int c = 0; c < 2; c++) {
        sa[c][ks] = __builtin_amdgcn_mfma_f32_16x16x32_bf16(qf[c][0], kf0, sa[c][ks], 0, 0, 0);
        sa[c][ks] = __builtin_amdgcn_mfma_f32_16x16x32_bf16(qf[c][1], kf1, sa[c][ks], 0, 0, 0);
      }
    }

    float mk2[4];
    #pragma unroll
    for (int ks = 0; ks < 4; ks++) mk2[ks] = mrow[kv0 + ks * 16 + lr] * LOG2E;

    // scale + mask + per-LANE local max (no tree on the common path)
    float tmax[2][4];
    #pragma unroll
    for (int c = 0; c < 2; c++) {
      #pragma unroll
      for (int r = 0; r < 4; r++) tmax[c][r] = -1e30f;
      #pragma unroll
      for (int ks = 0; ks < 4; ks++)
        #pragma unroll
        for (int r = 0; r < 4; r++) {
          const float v = fmaf(sa[c][ks][r], SCL, mk2[ks]);
          sa[c][ks][r] = v;
          tmax[c][r] = fmaxf(tmax[c][r], v);
        }
    }

    // T13 defer: __all over per-lane local maxima; tree only on rescale path
    float need = -1e30f;
    #pragma unroll
    for (int c = 0; c < 2; c++)
      #pragma unroll
      for (int r = 0; r < 4; r++) need = fmaxf(need, tmax[c][r] - mrun[c][r]);
    if (!__all(need <= 4.0f)) {
      #pragma unroll
      for (int c = 0; c < 2; c++)
        #pragma unroll
        for (int r = 0; r < 4; r++) {
          const float rowmax = dppmax16(tmax[c][r]);
          const float mnew = fmaxf(mrun[c][r], rowmax);
          const float alpha = fexp2(mrun[c][r] - mnew);
          mrun[c][r] = mnew;
          lrun[c][r] *= alpha;
          #pragma unroll
          for (int ds = 0; ds < 4; ds++) o[c][ds][r] *= alpha;
        }
    }

    // exp + per-lane sum accumulate; P -> LDS via f2b (verified path)
    #pragma unroll
    for (int c = 0; c < 2; c++)
      #pragma unroll
      for (int ks = 0; ks < 4; ks++)
        #pragma unroll
        for (int r = 0; r < 4; r++) {
          const float p = fexp2(sa[c][ks][r] - mrun[c][r]);
          lrun[c][r] += p;
          pt[wave][c * 16 + rb + r][ks * 16 + lr] = f2b(p);
        }

    bf16x8 pa[2][2];
    #pragma unroll
    for (int c = 0; c < 2; c++)
      #pragma unroll
      for (int ko = 0; ko < 2; ko++)
        pa[c][ko] = *reinterpret_cast<const bf16x8*>(&pt[wave][c * 16 + lr][ko * 32 + lk]);

    // O += P V — V fragments read ONCE, used by both chains
    #pragma unroll
    for (int ds = 0; ds < 4; ds++) {
      #pragma unroll
      for (int ko = 0; ko < 2; ko++) {
        const int vrow = ds * 16 + lr;
        const int vs = ((ko << 2) + g) ^ (vrow & 7);
        const bf16x8 vf = *reinterpret_cast<const bf16x8*>(&vc[vrow * 64 + (vs << 3)]);
        #pragma unroll
        for (int c = 0; c < 2; c++)
          o[c][ds] = __builtin_amdgcn_mfma_f32_16x16x32_bf16(pa[c][ko], vf, o[c][ds], 0, 0, 0);
      }
    }
  }

  // epilogue: ONE sum tree per (chain,row), then scale + store
  #pragma unroll
  for (int c = 0; c < 2; c++) {
    float inv[4];
    #pragma unroll
    for (int r = 0; r < 4; r++) inv[r] = 1.0f / dppsum16(lrun[c][r]);
    #pragma unroll
    for (int ds = 0; ds < 4; ds++)
      #pragma unroll
      for (int r = 0; r < 4; r++) {
        const int srow = qrow0 + c * 16 + rb + r;
        ctxb[(size_t)(b * SS + srow) * HID + h * HD + ds * 16 + lr] = f2b(o[c][ds][r] * inv[r]);
      }
  }
}

// ---------------- output projection (BK=64 swizzled staging, fp32 out) -----
__global__ __launch_bounds__(256)
void gemm_out(const u16* __restrict__ ab, const u16* __restrict__ wb,
              const float* __restrict__ bias, float* __restrict__ out) {
  const int m0 = blockIdx.x << 7;
  const int n0 = blockIdx.y << 6;

  __shared__ u16 at[128 * 64];   // 16KB, slot-swizzled
  __shared__ u16 bt[64 * 64];    // 8KB

  const int tid = threadIdx.x;
  const int wave = tid >> 6;
  const int lane = tid & 63;
  const int g = lane >> 4;
  const int wm = wave << 5;
  const int lr = lane & 15;
  const int rb = g << 2;
  const int lrow = lane >> 3;
  const int dslot = lane & 7;

  f32x4 acc[2][4] = {};

  for (int k0 = 0; k0 < HID; k0 += 64) {
    __syncthreads();
    #pragma unroll
    for (int i = 0; i < 4; i++) {
      const int row = wave * 32 + i * 8 + lrow;
      const int scol = (dslot ^ (row & 7)) << 3;
      gl_lds16(&ab[(size_t)(m0 + row) * HID + k0 + scol], at + wave * 2048 + i * 512);
    }
    #pragma unroll
    for (int i = 0; i < 2; i++) {
      const int row = wave * 16 + i * 8 + lrow;
      const int scol = (dslot ^ (row & 7)) << 3;
      gl_lds16(&wb[(size_t)(n0 + row) * HID + k0 + scol], bt + wave * 1024 + i * 512);
    }
    __syncthreads();
    #pragma unroll
    for (int kk = 0; kk < 2; kk++) {
      bf16x8 af[2], bfr[4];
      #pragma unroll
      for (int i = 0; i < 2; i++) {
        const int ra = wm + i * 16 + lr;
        const int sa_ = ((kk << 2) + g) ^ (ra & 7);
        af[i] = *reinterpret_cast<const bf16x8*>(&at[ra * 64 + (sa_ << 3)]);
      }
      #pragma unroll
      for (int j = 0; j < 4; j++) {
        const int rbw = j * 16 + lr;
        const int sb_ = ((kk << 2) + g) ^ (rbw & 7);
        bfr[j] = *reinterpret_cast<const bf16x8*>(&bt[rbw * 64 + (sb_ << 3)]);
      }
      #pragma unroll
      for (int i = 0; i < 2; i++)
        #pragma unroll
        for (int j = 0; j < 4; j++)
          acc[i][j] = __builtin_amdgcn_mfma_f32_16x16x32_bf16(af[i], bfr[j], acc[i][j], 0, 0, 0);
    }
  }

  #pragma unroll
  for (int i = 0; i < 2; i++)
    #pragma unroll
    for (int j = 0; j < 4; j++)
      #pragma unroll
      for (int r = 0; r < 4; r++) {
        const int m = m0 + wm + i * 16 + rb + r;
        const int n = n0 + j * 16 + lr;
        out[(size_t)m * HID + n] = acc[i][j][r] + bias[n];
      }
}

extern "C" void kernel_launch(void* const* d_in, const int* in_sizes, int n_in,
                              void* d_out, int out_size, void* d_ws, size_t ws_size,
                              hipStream_t stream) {
  const float* hs   = (const float*)d_in[0];
  const float* mask = (const float*)d_in[1];
  const float* wq   = (const float*)d_in[2];
  const float* bq   = (const float*)d_in[3];
  const float* wk   = (const float*)d_in[4];
  const float* bk   = (const float*)d_in[5];
  const float* wv   = (const float*)d_in[6];
  const float* bv   = (const float*)d_in[7];
  const float* wo   = (const float*)d_in[8];
  const float* bo   = (const float*)d_in[9];
  float* out = (float*)d_out;

  char* ws = (char*)d_ws;
  u16* xb   = (u16*)(ws);                         // 8 MB  [4096][1024]
  u16* ctxb = (u16*)(ws + ((size_t)8  << 20));    // 8 MB  [4096][1024]
  u16* qhb  = (u16*)(ws + ((size_t)16 << 20));    // 8 MB  [32][2048][64]
  u16* khb  = (u16*)(ws + ((size_t)24 << 20));    // 8 MB
  u16* vtb  = (u16*)(ws + ((size_t)32 << 20));    // 8 MB  [32][64][2048]
  u16* wqb  = (u16*)(ws + ((size_t)40 << 20));    // 2 MB each
  u16* wkb  = (u16*)(ws + ((size_t)42 << 20));
  u16* wvb  = (u16*)(ws + ((size_t)44 << 20));
  u16* wob  = (u16*)(ws + ((size_t)46 << 20));

  cvt_all<<<8192, 256, 0, stream>>>(hs, wq, wk, wv, wo, xb, wqb, wkb, wvb, wob);

  gemm_qkv<<<dim3(32, 24), 256, 0, stream>>>(xb, wqb, wkb, wvb, bq, bk, bv, qhb, khb, vtb);
  attn<<<512, 256, 0, stream>>>(qhb, khb, vtb, mask, ctxb);
  gemm_out<<<dim3(32, 16), 256, 0, stream>>>(ctxb, wob, bo, out);
}

// Round 19
// 135.372 us; speedup vs baseline: 1.0707x; 1.0408x over previous
//
#include <hip/hip_runtime.h>
#include <hip/hip_bf16.h>

typedef unsigned short u16;
typedef __attribute__((ext_vector_type(4))) float f32x4;
typedef __attribute__((ext_vector_type(8))) __bf16 bf16x8;

#define NH 16
#define HD 64
#define HID 1024
#define SS 2048
#define MM 4096

__device__ __forceinline__ u16 f2b(float f) {
  unsigned u = __builtin_bit_cast(unsigned, f);
  u += 0x7fff + ((u >> 16) & 1);   // RNE
  return (u16)(u >> 16);
}

__device__ __forceinline__ float fexp2(float x) {
#if __has_builtin(__builtin_amdgcn_exp2f)
  return __builtin_amdgcn_exp2f(x);
#else
  return exp2f(x);
#endif
}

// DPP lane-permute within a 16-lane row (VALU pipe — zero DS traffic)
template <int CTRL>
__device__ __forceinline__ float dpp_mv(float x) {
  int xi = __builtin_bit_cast(int, x);
  int yi = __builtin_amdgcn_update_dpp(xi, xi, CTRL, 0xF, 0xF, true);
  return __builtin_bit_cast(float, yi);
}
__device__ __forceinline__ float dppmax16(float v) {
  v = fmaxf(v, dpp_mv<0xB1>(v));
  v = fmaxf(v, dpp_mv<0x4E>(v));
  v = fmaxf(v, dpp_mv<0x141>(v));
  v = fmaxf(v, dpp_mv<0x140>(v));
  return v;
}
__device__ __forceinline__ float dppsum16(float v) {
  v += dpp_mv<0xB1>(v);
  v += dpp_mv<0x4E>(v);
  v += dpp_mv<0x141>(v);
  v += dpp_mv<0x140>(v);
  return v;
}

// async global -> LDS, 16B per lane (wave-uniform LDS base + lane*16)
__device__ __forceinline__ void gl_lds16(const u16* g, u16* l) {
  __builtin_amdgcn_global_load_lds(
      (const __attribute__((address_space(1))) void*)g,
      (__attribute__((address_space(3))) void*)l, 16, 0, 0);
}

// ---------------- fused fp32 -> bf16 conversion (x + 4 weights, 1 launch) ---
__global__ void cvt_all(const float* __restrict__ hs,
                        const float* __restrict__ wq, const float* __restrict__ wk,
                        const float* __restrict__ wv, const float* __restrict__ wo,
                        u16* __restrict__ xb, u16* __restrict__ wqb,
                        u16* __restrict__ wkb, u16* __restrict__ wvb,
                        u16* __restrict__ wob) {
  const int i = blockIdx.x * 256 + threadIdx.x;   // float4 index, 2M total
  const float* src; u16* dst; int off;
  if (i < 1048576) { src = hs; dst = xb; off = i; }
  else {
    const int j = i - 1048576;
    const int w = j >> 18;          // 262144 float4s per weight
    off = j & 262143;
    src = (w == 0) ? wq : (w == 1) ? wk : (w == 2) ? wv : wo;
    dst = (w == 0) ? wqb : (w == 1) ? wkb : (w == 2) ? wvb : wob;
  }
  float4 v = reinterpret_cast<const float4*>(src)[off];
  ushort4 o;
  o.x = f2b(v.x); o.y = f2b(v.y); o.z = f2b(v.z); o.w = f2b(v.w);
  reinterpret_cast<ushort4*>(dst)[off] = o;
}

// ---------------- Q/K projection (BK=64, swizzled gl_lds staging) -----------
__global__ __launch_bounds__(256)
void gemm_qk(const u16* __restrict__ xb,
             const u16* __restrict__ wqb, const u16* __restrict__ wkb,
             const float* __restrict__ bq, const float* __restrict__ bk,
             u16* __restrict__ qh, u16* __restrict__ kh) {
  const int mt = blockIdx.x;             // 0..31
  const int nt = blockIdx.y;             // 0..15
  const int wi = nt >> 3;                // 0=q 1=k
  const int n0 = (nt & 7) << 7;
  const int m0 = mt << 7;
  const u16* wb = (wi == 0) ? wqb : wkb;
  const float* bias = (wi == 0) ? bq : bk;
  u16* outp = (wi == 0) ? qh : kh;

  __shared__ u16 at[128 * 64];   // 16KB, slot-swizzled
  __shared__ u16 bt[128 * 64];

  const int tid = threadIdx.x;
  const int wave = tid >> 6;
  const int lane = tid & 63;
  const int g = lane >> 4;
  const int wm = (wave >> 1) << 6;
  const int wn = (wave & 1) << 6;
  const int lr = lane & 15;
  const int rb = g << 2;
  const int lrow = lane >> 3;
  const int dslot = lane & 7;

  f32x4 acc[4][4] = {};

  for (int k0 = 0; k0 < HID; k0 += 64) {
    __syncthreads();
    #pragma unroll
    for (int i = 0; i < 4; i++) {
      const int row = wave * 32 + i * 8 + lrow;
      const int scol = (dslot ^ (row & 7)) << 3;
      gl_lds16(&xb[(size_t)(m0 + row) * HID + k0 + scol], at + wave * 2048 + i * 512);
      gl_lds16(&wb[(size_t)(n0 + row) * HID + k0 + scol], bt + wave * 2048 + i * 512);
    }
    __syncthreads();
    #pragma unroll
    for (int kk = 0; kk < 2; kk++) {
      bf16x8 af[4], bfr[4];
      #pragma unroll
      for (int i = 0; i < 4; i++) {
        const int ra = wm + i * 16 + lr;
        const int rbw = wn + i * 16 + lr;
        const int sa_ = ((kk << 2) + g) ^ (ra & 7);
        const int sb_ = ((kk << 2) + g) ^ (rbw & 7);
        af[i]  = *reinterpret_cast<const bf16x8*>(&at[ra * 64 + (sa_ << 3)]);
        bfr[i] = *reinterpret_cast<const bf16x8*>(&bt[rbw * 64 + (sb_ << 3)]);
      }
      #pragma unroll
      for (int i = 0; i < 4; i++)
        #pragma unroll
        for (int j = 0; j < 4; j++)
          acc[i][j] = __builtin_amdgcn_mfma_f32_16x16x32_bf16(af[i], bfr[j], acc[i][j], 0, 0, 0);
    }
  }

  #pragma unroll
  for (int i = 0; i < 4; i++) {
    #pragma unroll
    for (int j = 0; j < 4; j++) {
      #pragma unroll
      for (int r = 0; r < 4; r++) {
        const int m = m0 + wm + i * 16 + rb + r;
        const int n = n0 + wn + j * 16 + lr;
        const float val = acc[i][j][r] + bias[n];
        const u16 bv16 = f2b(val);
        const int b = m >> 11, s = m & 2047;
        const int h = n >> 6, d = n & 63;
        outp[((size_t)(b * NH + h) * SS + s) * HD + d] = bv16;
      }
    }
  }
}

// ---------------- V projection (swapped-operand MFMA, transposed store) -----
// acc[i][j] = mfma(bfr[j], af[i]): output reg side = n-rows, lane side = m.
// vt store: lane index lr lands on s -> 4x32B contiguous segments per instr.
__global__ __launch_bounds__(256)
void gemm_v(const u16* __restrict__ xb, const u16* __restrict__ wvb,
            const float* __restrict__ bv, u16* __restrict__ vt) {
  const int mt = blockIdx.x;             // 0..31
  const int nt = blockIdx.y;             // 0..7
  const int n0 = nt << 7;
  const int m0 = mt << 7;

  __shared__ u16 at[128 * 64];
  __shared__ u16 bt[128 * 64];

  const int tid = threadIdx.x;
  const int wave = tid >> 6;
  const int lane = tid & 63;
  const int g = lane >> 4;
  const int wm = (wave >> 1) << 6;
  const int wn = (wave & 1) << 6;
  const int lr = lane & 15;
  const int rb = g << 2;
  const int lrow = lane >> 3;
  const int dslot = lane & 7;

  f32x4 acc[4][4] = {};

  for (int k0 = 0; k0 < HID; k0 += 64) {
    __syncthreads();
    #pragma unroll
    for (int i = 0; i < 4; i++) {
      const int row = wave * 32 + i * 8 + lrow;
      const int scol = (dslot ^ (row & 7)) << 3;
      gl_lds16(&xb[(size_t)(m0 + row) * HID + k0 + scol], at + wave * 2048 + i * 512);
      gl_lds16(&wvb[(size_t)(n0 + row) * HID + k0 + scol], bt + wave * 2048 + i * 512);
    }
    __syncthreads();
    #pragma unroll
    for (int kk = 0; kk < 2; kk++) {
      bf16x8 af[4], bfr[4];
      #pragma unroll
      for (int i = 0; i < 4; i++) {
        const int ra = wm + i * 16 + lr;
        const int rbw = wn + i * 16 + lr;
        const int sa_ = ((kk << 2) + g) ^ (ra & 7);
        const int sb_ = ((kk << 2) + g) ^ (rbw & 7);
        af[i]  = *reinterpret_cast<const bf16x8*>(&at[ra * 64 + (sa_ << 3)]);
        bfr[i] = *reinterpret_cast<const bf16x8*>(&bt[rbw * 64 + (sb_ << 3)]);
      }
      #pragma unroll
      for (int i = 0; i < 4; i++)
        #pragma unroll
        for (int j = 0; j < 4; j++)
          acc[i][j] = __builtin_amdgcn_mfma_f32_16x16x32_bf16(bfr[j], af[i], acc[i][j], 0, 0, 0);
    }
  }

  #pragma unroll
  for (int i = 0; i < 4; i++) {
    #pragma unroll
    for (int j = 0; j < 4; j++) {
      #pragma unroll
      for (int r = 0; r < 4; r++) {
        const int n = n0 + wn + j * 16 + rb + r;   // row side (1st operand)
        const int m = m0 + wm + i * 16 + lr;       // col side (2nd operand)
        const float val = acc[i][j][r] + bv[n];
        const u16 bv16 = f2b(val);
        const int b = m >> 11, s = m & 2047;
        const int h = n >> 6, d = n & 63;
        vt[((size_t)(b * NH + h) * HD + d) * SS + s] = bv16;
      }
    }
  }
}

// ---------------- flash attention v16: v12 math + 3-deep counted-vmcnt ------
__global__ __launch_bounds__(256, 2)
void attn(const u16* __restrict__ qh, const u16* __restrict__ kh, const u16* __restrict__ vt,
          const float* __restrict__ mask, u16* __restrict__ ctxb) {
  const int id = blockIdx.x;
  const int bh = (id & 7) + 8 * ((id >> 3) & 3);
  const int qt = id >> 5;                         // 0..15
  const int b = bh >> 4;
  const int h = bh & 15;
  const int q0 = qt << 7;                         // 128 q-rows per block

  const int tid = threadIdx.x;
  const int wave = tid >> 6;
  const int lane = tid & 63;
  const int g = lane >> 4;
  const int lr = lane & 15;
  const int lk = g << 3;
  const int rb = g << 2;
  const int lrow = lane >> 3;
  const int dslot = lane & 7;

  const u16* qb = qh + (size_t)bh * SS * HD;
  const u16* kb = kh + (size_t)bh * SS * HD;
  const u16* vb = vt + (size_t)bh * HD * SS;
  const float* mrow = mask + (size_t)b * SS;

  __shared__ u16 kt[3][64 * 64];     // K tile [kv][64d], swizzled, 8KB x3
  __shared__ u16 vtile[3][64 * 64];  // V^T tile [d][64kv], swizzled, 8KB x3
  __shared__ u16 pt[4][32][72];      // per-wave P buffer, 2 chains x 16 rows

  const int qrow0 = q0 + wave * 32;

  bf16x8 qf[2][2];
  #pragma unroll
  for (int c = 0; c < 2; c++)
    #pragma unroll
    for (int dk = 0; dk < 2; dk++)
      qf[c][dk] = *reinterpret_cast<const bf16x8*>(
          &qb[(size_t)(qrow0 + c * 16 + lr) * HD + dk * 32 + lk]);

  f32x4 o[2][4] = {};
  float mrun[2][4], lrun[2][4];   // lrun = per-LANE partial sums
  #pragma unroll
  for (int c = 0; c < 2; c++)
    #pragma unroll
    for (int r = 0; r < 4; r++) { mrun[c][r] = -1e30f; lrun[c][r] = 0.f; }

  const float LOG2E = 1.4426950408889634f;
  const float SCL = 0.125f * LOG2E;

  auto stage = [&](u16* kdst, u16* vdst, int kv0) {
    #pragma unroll
    for (int i = 0; i < 2; i++) {
      const int row = wave * 16 + i * 8 + lrow;
      const int scol = (dslot ^ (row & 7)) << 3;
      gl_lds16(&kb[(size_t)(kv0 + row) * HD + scol], kdst + wave * 1024 + i * 512);
      gl_lds16(&vb[(size_t)row * SS + kv0 + scol], vdst + wave * 1024 + i * 512);
    }
  };

  // prologue: 2 tiles in flight (8 gl_lds outstanding per wave)
  stage(kt[0], vtile[0], 0);
  stage(kt[1], vtile[1], 64);

  for (int it = 0; it < SS / 64; ++it) {
    if (it < SS / 64 - 1) asm volatile("s_waitcnt vmcnt(4)" ::: "memory");
    else                  asm volatile("s_waitcnt vmcnt(0)" ::: "memory");
    __builtin_amdgcn_s_barrier();

    const int cur = it % 3;
    if (it + 2 < SS / 64) {
      const int nxt = (it + 2) % 3;
      stage(kt[nxt], vtile[nxt], (it + 2) * 64);
    }

    const int kv0 = it * 64;
    const u16* kc = kt[cur];
    const u16* vc = vtile[cur];

    // S = Q K^T — K fragments read ONCE, used by both chains
    f32x4 sa[2][4] = {};
    #pragma unroll
    for (int ks = 0; ks < 4; ks++) {
      const int row = ks * 16 + lr;
      const int s0 = g ^ (row & 7);
      const int s1 = (g + 4) ^ (row & 7);
      const bf16x8 kf0 = *reinterpret_cast<const bf16x8*>(&kc[row * 64 + (s0 << 3)]);
      const bf16x8 kf1 = *reinterpret_cast<const bf16x8*>(&kc[row * 64 + (s1 << 3)]);
      #pragma unroll
      for (int c = 0; c < 2; c++) {
        sa[c][ks] = __builtin_amdgcn_mfma_f32_16x16x32_bf16(qf[c][0], kf0, sa[c][ks], 0, 0, 0);
        sa[c][ks] = __builtin_amdgcn_mfma_f32_16x16x32_bf16(qf[c][1], kf1, sa[c][ks], 0, 0, 0);
      }
    }

    float mk2[4];
    #pragma unroll
    for (int ks = 0; ks < 4; ks++) mk2[ks] = mrow[kv0 + ks * 16 + lr] * LOG2E;

    // scale + mask + per-LANE local max (no tree on the common path)
    float tmax[2][4];
    #pragma unroll
    for (int c = 0; c < 2; c++) {
      #pragma unroll
      for (int r = 0; r < 4; r++) tmax[c][r] = -1e30f;
      #pragma unroll
      for (int ks = 0; ks < 4; ks++)
        #pragma unroll
        for (int r = 0; r < 4; r++) {
          const float v = fmaf(sa[c][ks][r], SCL, mk2[ks]);
          sa[c][ks][r] = v;
          tmax[c][r] = fmaxf(tmax[c][r], v);
        }
    }

    // T13 defer: __all over per-lane local maxima; tree only on rescale path
    float need = -1e30f;
    #pragma unroll
    for (int c = 0; c < 2; c++)
      #pragma unroll
      for (int r = 0; r < 4; r++) need = fmaxf(need, tmax[c][r] - mrun[c][r]);
    if (!__all(need <= 4.0f)) {
      #pragma unroll
      for (int c = 0; c < 2; c++)
        #pragma unroll
        for (int r = 0; r < 4; r++) {
          const float rowmax = dppmax16(tmax[c][r]);
          const float mnew = fmaxf(mrun[c][r], rowmax);
          const float alpha = fexp2(mrun[c][r] - mnew);
          mrun[c][r] = mnew;
          lrun[c][r] *= alpha;
          #pragma unroll
          for (int ds = 0; ds < 4; ds++) o[c][ds][r] *= alpha;
        }
    }

    // exp + per-lane sum accumulate; P -> LDS via f2b (verified path)
    #pragma unroll
    for (int c = 0; c < 2; c++)
      #pragma unroll
      for (int ks = 0; ks < 4; ks++)
        #pragma unroll
        for (int r = 0; r < 4; r++) {
          const float p = fexp2(sa[c][ks][r] - mrun[c][r]);
          lrun[c][r] += p;
          pt[wave][c * 16 + rb + r][ks * 16 + lr] = f2b(p);
        }

    bf16x8 pa[2][2];
    #pragma unroll
    for (int c = 0; c < 2; c++)
      #pragma unroll
      for (int ko = 0; ko < 2; ko++)
        pa[c][ko] = *reinterpret_cast<const bf16x8*>(&pt[wave][c * 16 + lr][ko * 32 + lk]);

    // O += P V — V fragments read ONCE, used by both chains
    #pragma unroll
    for (int ds = 0; ds < 4; ds++) {
      #pragma unroll
      for (int ko = 0; ko < 2; ko++) {
        const int vrow = ds * 16 + lr;
        const int vs = ((ko << 2) + g) ^ (vrow & 7);
        const bf16x8 vf = *reinterpret_cast<const bf16x8*>(&vc[vrow * 64 + (vs << 3)]);
        #pragma unroll
        for (int c = 0; c < 2; c++)
          o[c][ds] = __builtin_amdgcn_mfma_f32_16x16x32_bf16(pa[c][ko], vf, o[c][ds], 0, 0, 0);
      }
    }
  }

  // epilogue: ONE sum tree per (chain,row), then scale + store
  #pragma unroll
  for (int c = 0; c < 2; c++) {
    float inv[4];
    #pragma unroll
    for (int r = 0; r < 4; r++) inv[r] = 1.0f / dppsum16(lrun[c][r]);
    #pragma unroll
    for (int ds = 0; ds < 4; ds++)
      #pragma unroll
      for (int r = 0; r < 4; r++) {
        const int srow = qrow0 + c * 16 + rb + r;
        ctxb[(size_t)(b * SS + srow) * HID + h * HD + ds * 16 + lr] = f2b(o[c][ds][r] * inv[r]);
      }
  }
}

// ---------------- output projection (BK=64 swizzled staging, fp32 out) -----
__global__ __launch_bounds__(256)
void gemm_out(const u16* __restrict__ ab, const u16* __restrict__ wb,
              const float* __restrict__ bias, float* __restrict__ out) {
  const int m0 = blockIdx.x << 7;
  const int n0 = blockIdx.y << 6;

  __shared__ u16 at[128 * 64];   // 16KB, slot-swizzled
  __shared__ u16 bt[64 * 64];    // 8KB

  const int tid = threadIdx.x;
  const int wave = tid >> 6;
  const int lane = tid & 63;
  const int g = lane >> 4;
  const int wm = wave << 5;
  const int lr = lane & 15;
  const int rb = g << 2;
  const int lrow = lane >> 3;
  const int dslot = lane & 7;

  f32x4 acc[2][4] = {};

  for (int k0 = 0; k0 < HID; k0 += 64) {
    __syncthreads();
    #pragma unroll
    for (int i = 0; i < 4; i++) {
      const int row = wave * 32 + i * 8 + lrow;
      const int scol = (dslot ^ (row & 7)) << 3;
      gl_lds16(&ab[(size_t)(m0 + row) * HID + k0 + scol], at + wave * 2048 + i * 512);
    }
    #pragma unroll
    for (int i = 0; i < 2; i++) {
      const int row = wave * 16 + i * 8 + lrow;
      const int scol = (dslot ^ (row & 7)) << 3;
      gl_lds16(&wb[(size_t)(n0 + row) * HID + k0 + scol], bt + wave * 1024 + i * 512);
    }
    __syncthreads();
    #pragma unroll
    for (int kk = 0; kk < 2; kk++) {
      bf16x8 af[2], bfr[4];
      #pragma unroll
      for (int i = 0; i < 2; i++) {
        const int ra = wm + i * 16 + lr;
        const int sa_ = ((kk << 2) + g) ^ (ra & 7);
        af[i] = *reinterpret_cast<const bf16x8*>(&at[ra * 64 + (sa_ << 3)]);
      }
      #pragma unroll
      for (int j = 0; j < 4; j++) {
        const int rbw = j * 16 + lr;
        const int sb_ = ((kk << 2) + g) ^ (rbw & 7);
        bfr[j] = *reinterpret_cast<const bf16x8*>(&bt[rbw * 64 + (sb_ << 3)]);
      }
      #pragma unroll
      for (int i = 0; i < 2; i++)
        #pragma unroll
        for (int j = 0; j < 4; j++)
          acc[i][j] = __builtin_amdgcn_mfma_f32_16x16x32_bf16(af[i], bfr[j], acc[i][j], 0, 0, 0);
    }
  }

  #pragma unroll
  for (int i = 0; i < 2; i++)
    #pragma unroll
    for (int j = 0; j < 4; j++)
      #pragma unroll
      for (int r = 0; r < 4; r++) {
        const int m = m0 + wm + i * 16 + rb + r;
        const int n = n0 + j * 16 + lr;
        out[(size_t)m * HID + n] = acc[i][j][r] + bias[n];
      }
}

extern "C" void kernel_launch(void* const* d_in, const int* in_sizes, int n_in,
                              void* d_out, int out_size, void* d_ws, size_t ws_size,
                              hipStream_t stream) {
  const float* hs   = (const float*)d_in[0];
  const float* mask = (const float*)d_in[1];
  const float* wq   = (const float*)d_in[2];
  const float* bq   = (const float*)d_in[3];
  const float* wk   = (const float*)d_in[4];
  const float* bk   = (const float*)d_in[5];
  const float* wv   = (const float*)d_in[6];
  const float* bv   = (const float*)d_in[7];
  const float* wo   = (const float*)d_in[8];
  const float* bo   = (const float*)d_in[9];
  float* out = (float*)d_out;

  char* ws = (char*)d_ws;
  u16* xb   = (u16*)(ws);                         // 8 MB  [4096][1024]
  u16* ctxb = (u16*)(ws + ((size_t)8  << 20));    // 8 MB  [4096][1024]
  u16* qhb  = (u16*)(ws + ((size_t)16 << 20));    // 8 MB  [32][2048][64]
  u16* khb  = (u16*)(ws + ((size_t)24 << 20));    // 8 MB
  u16* vtb  = (u16*)(ws + ((size_t)32 << 20));    // 8 MB  [32][64][2048]
  u16* wqb  = (u16*)(ws + ((size_t)40 << 20));    // 2 MB each
  u16* wkb  = (u16*)(ws + ((size_t)42 << 20));
  u16* wvb  = (u16*)(ws + ((size_t)44 << 20));
  u16* wob  = (u16*)(ws + ((size_t)46 << 20));

  cvt_all<<<8192, 256, 0, stream>>>(hs, wq, wk, wv, wo, xb, wqb, wkb, wvb, wob);

  gemm_qk<<<dim3(32, 16), 256, 0, stream>>>(xb, wqb, wkb, bq, bk, qhb, khb);
  gemm_v<<<dim3(32, 8), 256, 0, stream>>>(xb, wvb, bv, vtb);
  attn<<<512, 256, 0, stream>>>(qhb, khb, vtb, mask, ctxb);
  gemm_out<<<dim3(32, 16), 256, 0, stream>>>(ctxb, wob, bo, out);
}

// Round 20
// 132.255 us; speedup vs baseline: 1.0959x; 1.0236x over previous
//
#include <hip/hip_runtime.h>
#include <hip/hip_bf16.h>

typedef unsigned short u16;
typedef __attribute__((ext_vector_type(4))) float f32x4;
typedef __attribute__((ext_vector_type(8))) __bf16 bf16x8;

#define NH 16
#define HD 64
#define HID 1024
#define SS 2048
#define MM 4096

__device__ __forceinline__ u16 f2b(float f) {
  unsigned u = __builtin_bit_cast(unsigned, f);
  u += 0x7fff + ((u >> 16) & 1);   // RNE
  return (u16)(u >> 16);
}

__device__ __forceinline__ float fexp2(float x) {
#if __has_builtin(__builtin_amdgcn_exp2f)
  return __builtin_amdgcn_exp2f(x);
#else
  return exp2f(x);
#endif
}

// DPP lane-permute within a 16-lane row (VALU pipe — zero DS traffic)
template <int CTRL>
__device__ __forceinline__ float dpp_mv(float x) {
  int xi = __builtin_bit_cast(int, x);
  int yi = __builtin_amdgcn_update_dpp(xi, xi, CTRL, 0xF, 0xF, true);
  return __builtin_bit_cast(float, yi);
}
__device__ __forceinline__ float dppmax16(float v) {
  v = fmaxf(v, dpp_mv<0xB1>(v));
  v = fmaxf(v, dpp_mv<0x4E>(v));
  v = fmaxf(v, dpp_mv<0x141>(v));
  v = fmaxf(v, dpp_mv<0x140>(v));
  return v;
}
__device__ __forceinline__ float dppsum16(float v) {
  v += dpp_mv<0xB1>(v);
  v += dpp_mv<0x4E>(v);
  v += dpp_mv<0x141>(v);
  v += dpp_mv<0x140>(v);
  return v;
}

// async global -> LDS, 16B per lane (wave-uniform LDS base + lane*16)
__device__ __forceinline__ void gl_lds16(const u16* g, u16* l) {
  __builtin_amdgcn_global_load_lds(
      (const __attribute__((address_space(1))) void*)g,
      (__attribute__((address_space(3))) void*)l, 16, 0, 0);
}

// ---------------- fused fp32 -> bf16 conversion (x + 4 weights, 1 launch) ---
__global__ void cvt_all(const float* __restrict__ hs,
                        const float* __restrict__ wq, const float* __restrict__ wk,
                        const float* __restrict__ wv, const float* __restrict__ wo,
                        u16* __restrict__ xb, u16* __restrict__ wqb,
                        u16* __restrict__ wkb, u16* __restrict__ wvb,
                        u16* __restrict__ wob) {
  const int i = blockIdx.x * 256 + threadIdx.x;   // float4 index, 2M total
  const float* src; u16* dst; int off;
  if (i < 1048576) { src = hs; dst = xb; off = i; }
  else {
    const int j = i - 1048576;
    const int w = j >> 18;          // 262144 float4s per weight
    off = j & 262143;
    src = (w == 0) ? wq : (w == 1) ? wk : (w == 2) ? wv : wo;
    dst = (w == 0) ? wqb : (w == 1) ? wkb : (w == 2) ? wvb : wob;
  }
  float4 v = reinterpret_cast<const float4*>(src)[off];
  ushort4 o;
  o.x = f2b(v.x); o.y = f2b(v.y); o.z = f2b(v.z); o.w = f2b(v.w);
  reinterpret_cast<ushort4*>(dst)[off] = o;
}

// ---------------- merged QKV projection: top-level branch, grid 32x24 -------
// Path A (wi<2): round-19 gemm_qk verbatim. Path B (wi==2): round-19 gemm_v
// verbatim (swapped-operand MFMA -> contiguous vt store). Block-uniform
// branch, no inner-loop divergence; packs 3 blocks/CU for the whole phase.
__global__ __launch_bounds__(256)
void gemm_qkv(const u16* __restrict__ xb,
              const u16* __restrict__ wqb, const u16* __restrict__ wkb, const u16* __restrict__ wvb,
              const float* __restrict__ bq, const float* __restrict__ bk, const float* __restrict__ bv,
              u16* __restrict__ qh, u16* __restrict__ kh, u16* __restrict__ vt) {
  const int mt = blockIdx.x;             // 0..31
  const int nt = blockIdx.y;             // 0..23
  const int wi = nt >> 3;                // 0=q 1=k 2=v
  const int n0 = (nt & 7) << 7;
  const int m0 = mt << 7;

  __shared__ u16 at[128 * 64];   // 16KB, slot-swizzled
  __shared__ u16 bt[128 * 64];

  const int tid = threadIdx.x;
  const int wave = tid >> 6;
  const int lane = tid & 63;
  const int g = lane >> 4;
  const int wm = (wave >> 1) << 6;
  const int wn = (wave & 1) << 6;
  const int lr = lane & 15;
  const int rb = g << 2;
  const int lrow = lane >> 3;
  const int dslot = lane & 7;

  if (wi < 2) {
    // ---------------- Q/K path (round-19 gemm_qk) ----------------
    const u16* wb = (wi == 0) ? wqb : wkb;
    const float* bias = (wi == 0) ? bq : bk;
    u16* outp = (wi == 0) ? qh : kh;

    f32x4 acc[4][4] = {};

    for (int k0 = 0; k0 < HID; k0 += 64) {
      __syncthreads();
      #pragma unroll
      for (int i = 0; i < 4; i++) {
        const int row = wave * 32 + i * 8 + lrow;
        const int scol = (dslot ^ (row & 7)) << 3;
        gl_lds16(&xb[(size_t)(m0 + row) * HID + k0 + scol], at + wave * 2048 + i * 512);
        gl_lds16(&wb[(size_t)(n0 + row) * HID + k0 + scol], bt + wave * 2048 + i * 512);
      }
      __syncthreads();
      #pragma unroll
      for (int kk = 0; kk < 2; kk++) {
        bf16x8 af[4], bfr[4];
        #pragma unroll
        for (int i = 0; i < 4; i++) {
          const int ra = wm + i * 16 + lr;
          const int rbw = wn + i * 16 + lr;
          const int sa_ = ((kk << 2) + g) ^ (ra & 7);
          const int sb_ = ((kk << 2) + g) ^ (rbw & 7);
          af[i]  = *reinterpret_cast<const bf16x8*>(&at[ra * 64 + (sa_ << 3)]);
          bfr[i] = *reinterpret_cast<const bf16x8*>(&bt[rbw * 64 + (sb_ << 3)]);
        }
        #pragma unroll
        for (int i = 0; i < 4; i++)
          #pragma unroll
          for (int j = 0; j < 4; j++)
            acc[i][j] = __builtin_amdgcn_mfma_f32_16x16x32_bf16(af[i], bfr[j], acc[i][j], 0, 0, 0);
      }
    }

    #pragma unroll
    for (int i = 0; i < 4; i++) {
      #pragma unroll
      for (int j = 0; j < 4; j++) {
        #pragma unroll
        for (int r = 0; r < 4; r++) {
          const int m = m0 + wm + i * 16 + rb + r;
          const int n = n0 + wn + j * 16 + lr;
          const float val = acc[i][j][r] + bias[n];
          const u16 bv16 = f2b(val);
          const int b = m >> 11, s = m & 2047;
          const int h = n >> 6, d = n & 63;
          outp[((size_t)(b * NH + h) * SS + s) * HD + d] = bv16;
        }
      }
    }
  } else {
    // ---------------- V path (round-19 gemm_v, swapped operands) -----------
    f32x4 acc[4][4] = {};

    for (int k0 = 0; k0 < HID; k0 += 64) {
      __syncthreads();
      #pragma unroll
      for (int i = 0; i < 4; i++) {
        const int row = wave * 32 + i * 8 + lrow;
        const int scol = (dslot ^ (row & 7)) << 3;
        gl_lds16(&xb[(size_t)(m0 + row) * HID + k0 + scol], at + wave * 2048 + i * 512);
        gl_lds16(&wvb[(size_t)(n0 + row) * HID + k0 + scol], bt + wave * 2048 + i * 512);
      }
      __syncthreads();
      #pragma unroll
      for (int kk = 0; kk < 2; kk++) {
        bf16x8 af[4], bfr[4];
        #pragma unroll
        for (int i = 0; i < 4; i++) {
          const int ra = wm + i * 16 + lr;
          const int rbw = wn + i * 16 + lr;
          const int sa_ = ((kk << 2) + g) ^ (ra & 7);
          const int sb_ = ((kk << 2) + g) ^ (rbw & 7);
          af[i]  = *reinterpret_cast<const bf16x8*>(&at[ra * 64 + (sa_ << 3)]);
          bfr[i] = *reinterpret_cast<const bf16x8*>(&bt[rbw * 64 + (sb_ << 3)]);
        }
        #pragma unroll
        for (int i = 0; i < 4; i++)
          #pragma unroll
          for (int j = 0; j < 4; j++)
            acc[i][j] = __builtin_amdgcn_mfma_f32_16x16x32_bf16(bfr[j], af[i], acc[i][j], 0, 0, 0);
      }
    }

    #pragma unroll
    for (int i = 0; i < 4; i++) {
      #pragma unroll
      for (int j = 0; j < 4; j++) {
        #pragma unroll
        for (int r = 0; r < 4; r++) {
          const int n = n0 + wn + j * 16 + rb + r;   // row side (1st operand)
          const int m = m0 + wm + i * 16 + lr;       // col side (2nd operand)
          const float val = acc[i][j][r] + bv[n];
          const u16 bv16 = f2b(val);
          const int b = m >> 11, s = m & 2047;
          const int h = n >> 6, d = n & 63;
          vt[((size_t)(b * NH + h) * HD + d) * SS + s] = bv16;
        }
      }
    }
  }
}

// ---------------- flash attention v16: v12 math + 3-deep counted-vmcnt ------
__global__ __launch_bounds__(256, 2)
void attn(const u16* __restrict__ qh, const u16* __restrict__ kh, const u16* __restrict__ vt,
          const float* __restrict__ mask, u16* __restrict__ ctxb) {
  const int id = blockIdx.x;
  const int bh = (id & 7) + 8 * ((id >> 3) & 3);
  const int qt = id >> 5;                         // 0..15
  const int b = bh >> 4;
  const int h = bh & 15;
  const int q0 = qt << 7;                         // 128 q-rows per block

  const int tid = threadIdx.x;
  const int wave = tid >> 6;
  const int lane = tid & 63;
  const int g = lane >> 4;
  const int lr = lane & 15;
  const int lk = g << 3;
  const int rb = g << 2;
  const int lrow = lane >> 3;
  const int dslot = lane & 7;

  const u16* qb = qh + (size_t)bh * SS * HD;
  const u16* kb = kh + (size_t)bh * SS * HD;
  const u16* vb = vt + (size_t)bh * HD * SS;
  const float* mrow = mask + (size_t)b * SS;

  __shared__ u16 kt[3][64 * 64];     // K tile [kv][64d], swizzled, 8KB x3
  __shared__ u16 vtile[3][64 * 64];  // V^T tile [d][64kv], swizzled, 8KB x3
  __shared__ u16 pt[4][32][72];      // per-wave P buffer, 2 chains x 16 rows

  const int qrow0 = q0 + wave * 32;

  bf16x8 qf[2][2];
  #pragma unroll
  for (int c = 0; c < 2; c++)
    #pragma unroll
    for (int dk = 0; dk < 2; dk++)
      qf[c][dk] = *reinterpret_cast<const bf16x8*>(
          &qb[(size_t)(qrow0 + c * 16 + lr) * HD + dk * 32 + lk]);

  f32x4 o[2][4] = {};
  float mrun[2][4], lrun[2][4];   // lrun = per-LANE partial sums
  #pragma unroll
  for (int c = 0; c < 2; c++)
    #pragma unroll
    for (int r = 0; r < 4; r++) { mrun[c][r] = -1e30f; lrun[c][r] = 0.f; }

  const float LOG2E = 1.4426950408889634f;
  const float SCL = 0.125f * LOG2E;

  auto stage = [&](u16* kdst, u16* vdst, int kv0) {
    #pragma unroll
    for (int i = 0; i < 2; i++) {
      const int row = wave * 16 + i * 8 + lrow;
      const int scol = (dslot ^ (row & 7)) << 3;
      gl_lds16(&kb[(size_t)(kv0 + row) * HD + scol], kdst + wave * 1024 + i * 512);
      gl_lds16(&vb[(size_t)row * SS + kv0 + scol], vdst + wave * 1024 + i * 512);
    }
  };

  // prologue: 2 tiles in flight (8 gl_lds outstanding per wave)
  stage(kt[0], vtile[0], 0);
  stage(kt[1], vtile[1], 64);

  for (int it = 0; it < SS / 64; ++it) {
    if (it < SS / 64 - 1) asm volatile("s_waitcnt vmcnt(4)" ::: "memory");
    else                  asm volatile("s_waitcnt vmcnt(0)" ::: "memory");
    __builtin_amdgcn_s_barrier();

    const int cur = it % 3;
    if (it + 2 < SS / 64) {
      const int nxt = (it + 2) % 3;
      stage(kt[nxt], vtile[nxt], (it + 2) * 64);
    }

    const int kv0 = it * 64;
    const u16* kc = kt[cur];
    const u16* vc = vtile[cur];

    // S = Q K^T — K fragments read ONCE, used by both chains
    f32x4 sa[2][4] = {};
    #pragma unroll
    for (int ks = 0; ks < 4; ks++) {
      const int row = ks * 16 + lr;
      const int s0 = g ^ (row & 7);
      const int s1 = (g + 4) ^ (row & 7);
      const bf16x8 kf0 = *reinterpret_cast<const bf16x8*>(&kc[row * 64 + (s0 << 3)]);
      const bf16x8 kf1 = *reinterpret_cast<const bf16x8*>(&kc[row * 64 + (s1 << 3)]);
      #pragma unroll
      for (int c = 0; c < 2; c++) {
        sa[c][ks] = __builtin_amdgcn_mfma_f32_16x16x32_bf16(qf[c][0], kf0, sa[c][ks], 0, 0, 0);
        sa[c][ks] = __builtin_amdgcn_mfma_f32_16x16x32_bf16(qf[c][1], kf1, sa[c][ks], 0, 0, 0);
      }
    }

    float mk2[4];
    #pragma unroll
    for (int ks = 0; ks < 4; ks++) mk2[ks] = mrow[kv0 + ks * 16 + lr] * LOG2E;

    // scale + mask + per-LANE local max (no tree on the common path)
    float tmax[2][4];
    #pragma unroll
    for (int c = 0; c < 2; c++) {
      #pragma unroll
      for (int r = 0; r < 4; r++) tmax[c][r] = -1e30f;
      #pragma unroll
      for (int ks = 0; ks < 4; ks++)
        #pragma unroll
        for (int r = 0; r < 4; r++) {
          const float v = fmaf(sa[c][ks][r], SCL, mk2[ks]);
          sa[c][ks][r] = v;
          tmax[c][r] = fmaxf(tmax[c][r], v);
        }
    }

    // T13 defer: __all over per-lane local maxima; tree only on rescale path
    float need = -1e30f;
    #pragma unroll
    for (int c = 0; c < 2; c++)
      #pragma unroll
      for (int r = 0; r < 4; r++) need = fmaxf(need, tmax[c][r] - mrun[c][r]);
    if (!__all(need <= 4.0f)) {
      #pragma unroll
      for (int c = 0; c < 2; c++)
        #pragma unroll
        for (int r = 0; r < 4; r++) {
          const float rowmax = dppmax16(tmax[c][r]);
          const float mnew = fmaxf(mrun[c][r], rowmax);
          const float alpha = fexp2(mrun[c][r] - mnew);
          mrun[c][r] = mnew;
          lrun[c][r] *= alpha;
          #pragma unroll
          for (int ds = 0; ds < 4; ds++) o[c][ds][r] *= alpha;
        }
    }

    // exp + per-lane sum accumulate; P -> LDS via f2b (verified path)
    #pragma unroll
    for (int c = 0; c < 2; c++)
      #pragma unroll
      for (int ks = 0; ks < 4; ks++)
        #pragma unroll
        for (int r = 0; r < 4; r++) {
          const float p = fexp2(sa[c][ks][r] - mrun[c][r]);
          lrun[c][r] += p;
          pt[wave][c * 16 + rb + r][ks * 16 + lr] = f2b(p);
        }

    bf16x8 pa[2][2];
    #pragma unroll
    for (int c = 0; c < 2; c++)
      #pragma unroll
      for (int ko = 0; ko < 2; ko++)
        pa[c][ko] = *reinterpret_cast<const bf16x8*>(&pt[wave][c * 16 + lr][ko * 32 + lk]);

    // O += P V — V fragments read ONCE, used by both chains
    #pragma unroll
    for (int ds = 0; ds < 4; ds++) {
      #pragma unroll
      for (int ko = 0; ko < 2; ko++) {
        const int vrow = ds * 16 + lr;
        const int vs = ((ko << 2) + g) ^ (vrow & 7);
        const bf16x8 vf = *reinterpret_cast<const bf16x8*>(&vc[vrow * 64 + (vs << 3)]);
        #pragma unroll
        for (int c = 0; c < 2; c++)
          o[c][ds] = __builtin_amdgcn_mfma_f32_16x16x32_bf16(pa[c][ko], vf, o[c][ds], 0, 0, 0);
      }
    }
  }

  // epilogue: ONE sum tree per (chain,row), then scale + store
  #pragma unroll
  for (int c = 0; c < 2; c++) {
    float inv[4];
    #pragma unroll
    for (int r = 0; r < 4; r++) inv[r] = 1.0f / dppsum16(lrun[c][r]);
    #pragma unroll
    for (int ds = 0; ds < 4; ds++)
      #pragma unroll
      for (int r = 0; r < 4; r++) {
        const int srow = qrow0 + c * 16 + rb + r;
        ctxb[(size_t)(b * SS + srow) * HID + h * HD + ds * 16 + lr] = f2b(o[c][ds][r] * inv[r]);
      }
  }
}

// ---------------- output projection (BK=64 swizzled staging, fp32 out) -----
__global__ __launch_bounds__(256)
void gemm_out(const u16* __restrict__ ab, const u16* __restrict__ wb,
              const float* __restrict__ bias, float* __restrict__ out) {
  const int m0 = blockIdx.x << 7;
  const int n0 = blockIdx.y << 6;

  __shared__ u16 at[128 * 64];   // 16KB, slot-swizzled
  __shared__ u16 bt[64 * 64];    // 8KB

  const int tid = threadIdx.x;
  const int wave = tid >> 6;
  const int lane = tid & 63;
  const int g = lane >> 4;
  const int wm = wave << 5;
  const int lr = lane & 15;
  const int rb = g << 2;
  const int lrow = lane >> 3;
  const int dslot = lane & 7;

  f32x4 acc[2][4] = {};

  for (int k0 = 0; k0 < HID; k0 += 64) {
    __syncthreads();
    #pragma unroll
    for (int i = 0; i < 4; i++) {
      const int row = wave * 32 + i * 8 + lrow;
      const int scol = (dslot ^ (row & 7)) << 3;
      gl_lds16(&ab[(size_t)(m0 + row) * HID + k0 + scol], at + wave * 2048 + i * 512);
    }
    #pragma unroll
    for (int i = 0; i < 2; i++) {
      const int row = wave * 16 + i * 8 + lrow;
      const int scol = (dslot ^ (row & 7)) << 3;
      gl_lds16(&wb[(size_t)(n0 + row) * HID + k0 + scol], bt + wave * 1024 + i * 512);
    }
    __syncthreads();
    #pragma unroll
    for (int kk = 0; kk < 2; kk++) {
      bf16x8 af[2], bfr[4];
      #pragma unroll
      for (int i = 0; i < 2; i++) {
        const int ra = wm + i * 16 + lr;
        const int sa_ = ((kk << 2) + g) ^ (ra & 7);
        af[i] = *reinterpret_cast<const bf16x8*>(&at[ra * 64 + (sa_ << 3)]);
      }
      #pragma unroll
      for (int j = 0; j < 4; j++) {
        const int rbw = j * 16 + lr;
        const int sb_ = ((kk << 2) + g) ^ (rbw & 7);
        bfr[j] = *reinterpret_cast<const bf16x8*>(&bt[rbw * 64 + (sb_ << 3)]);
      }
      #pragma unroll
      for (int i = 0; i < 2; i++)
        #pragma unroll
        for (int j = 0; j < 4; j++)
          acc[i][j] = __builtin_amdgcn_mfma_f32_16x16x32_bf16(af[i], bfr[j], acc[i][j], 0, 0, 0);
    }
  }

  #pragma unroll
  for (int i = 0; i < 2; i++)
    #pragma unroll
    for (int j = 0; j < 4; j++)
      #pragma unroll
      for (int r = 0; r < 4; r++) {
        const int m = m0 + wm + i * 16 + rb + r;
        const int n = n0 + j * 16 + lr;
        out[(size_t)m * HID + n] = acc[i][j][r] + bias[n];
      }
}

extern "C" void kernel_launch(void* const* d_in, const int* in_sizes, int n_in,
                              void* d_out, int out_size, void* d_ws, size_t ws_size,
                              hipStream_t stream) {
  const float* hs   = (const float*)d_in[0];
  const float* mask = (const float*)d_in[1];
  const float* wq   = (const float*)d_in[2];
  const float* bq   = (const float*)d_in[3];
  const float* wk   = (const float*)d_in[4];
  const float* bk   = (const float*)d_in[5];
  const float* wv   = (const float*)d_in[6];
  const float* bv   = (const float*)d_in[7];
  const float* wo   = (const float*)d_in[8];
  const float* bo   = (const float*)d_in[9];
  float* out = (float*)d_out;

  char* ws = (char*)d_ws;
  u16* xb   = (u16*)(ws);                         // 8 MB  [4096][1024]
  u16* ctxb = (u16*)(ws + ((size_t)8  << 20));    // 8 MB  [4096][1024]
  u16* qhb  = (u16*)(ws + ((size_t)16 << 20));    // 8 MB  [32][2048][64]
  u16* khb  = (u16*)(ws + ((size_t)24 << 20));    // 8 MB
  u16* vtb  = (u16*)(ws + ((size_t)32 << 20));    // 8 MB  [32][64][2048]
  u16* wqb  = (u16*)(ws + ((size_t)40 << 20));    // 2 MB each
  u16* wkb  = (u16*)(ws + ((size_t)42 << 20));
  u16* wvb  = (u16*)(ws + ((size_t)44 << 20));
  u16* wob  = (u16*)(ws + ((size_t)46 << 20));

  cvt_all<<<8192, 256, 0, stream>>>(hs, wq, wk, wv, wo, xb, wqb, wkb, wvb, wob);

  gemm_qkv<<<dim3(32, 24), 256, 0, stream>>>(xb, wqb, wkb, wvb, bq, bk, bv, qhb, khb, vtb);
  attn<<<512, 256, 0, stream>>>(qhb, khb, vtb, mask, ctxb);
  gemm_out<<<dim3(32, 16), 256, 0, stream>>>(ctxb, wob, bo, out);
}